// Round 5
// baseline (362.583 us; speedup 1.0000x reference)
//
#include <hip/hip_runtime.h>
#include <hip/hip_bf16.h>
#include <hip/hip_cooperative_groups.h>

namespace cg = cooperative_groups;

// GCN forward, algebraically collapsed (no nonlinearity between convs, mean pool):
//   g = (1/n)*((A^T u)^T X)@W1@W2 + (1/n)*(sum u)*(b1@W2) + b2,  A = D^-1/2(Adj+I)D^-1/2
// Round 5: ONE cooperative kernel. 7 grid.sync()s replace 12 graph gaps; the
// M=W1@W2 precompute overlaps the first edge scatter; head reads only M+Wd1.

#define D_IN 128
#define D_HID 256
#define D_DENSE 128
#define NB 16384      // LDS histogram bins (floats) = 64 KB
#define RS 128        // scatter blocks == partial replicas
#define RPG 16        // replicas folded per rgroup (RS/8)
#define FOLD_C 128    // nodes per fold block

struct Params {
    const float* x; const int* row; const int* col; const float* w;
    const float* W1; const float* b1; const float* W2; const float* b2;
    const float* Wd1; const float* bd1; const float* Wd2; const float* bd2;
    float* out;
    float* part; float* dinv; float* u; float* wv;
    float* s_part; float* S_u_part; float* M; float* c2;
    int N; int E; float inv_n;
};

__global__ __launch_bounds__(1024) void k_fused(Params p) {
    cg::grid_group grid = cg::this_grid();
    __shared__ float lds[NB];
    const int b = blockIdx.x, tid = threadIdx.x;
    const int N = p.N, E = p.E;
    const int nfold = (N + FOLD_C - 1) / FOLD_C;     // 157

    // ---- privatized edge scatter into replica b (blocks 0..RS-1) ----------
    auto scatter = [&](const int* tgt, const int* src, int mode) {
        int per = (E + RS - 1) / RS;
        int e0 = b * per, e1 = min(e0 + per, E);
        float* outp = p.part + (size_t)b * N;
        for (int base = 0; base < N; base += NB) {
            int lim = min(NB, N - base);
            for (int i = tid; i < lim; i += 1024) lds[i] = 0.f;
            __syncthreads();
            for (int e = e0 + tid; e < e1; e += 1024) {
                int t = tgt[e] - base;
                if ((unsigned)t < (unsigned)lim) {
                    float v = p.w[e];
                    if (mode != 0) {
                        int c = src[e];
                        float dc = p.dinv[c];
                        v *= (mode == 2) ? dc * p.u[c] : dc;
                    }
                    atomicAdd(&lds[t], v);           // LDS atomic
                }
            }
            __syncthreads();
            for (int i = tid; i < lim; i += 1024) outp[base + i] = lds[i];
            __syncthreads();
        }
    };

    // ---- fold RS replicas + node math (blocks 0..nfold-1) ------------------
    auto fold = [&](int mode) {
        if (b >= nfold) return;
        int j = tid & 127, rg = tid >> 7;
        int i = b * FOLD_C + j;
        bool act = i < N;
        float sv = 0.f;
        if (act) {
            const float* pp = p.part + (size_t)(rg * RPG) * N + i;
            #pragma unroll
            for (int r = 0; r < RPG; ++r) sv += pp[(size_t)r * N];
        }
        lds[rg * 128 + j] = sv;
        __syncthreads();
        float ui = 0.f;
        if (rg == 0) {
            float tot = 0.f;
            #pragma unroll
            for (int q = 0; q < 8; ++q) tot += lds[q * 128 + j];
            if (act) {
                if (mode == 0) p.dinv[i] = rsqrtf(tot + 1.0f);     // +1 self-loop
                else if (mode == 1) { float d = p.dinv[i]; ui = d * (tot + d); p.u[i] = ui; }
                else { float d = p.dinv[i]; p.wv[i] = d * (tot + d * p.u[i]); }
            }
            lds[1024 + j] = ui;
        }
        __syncthreads();
        if (mode == 1) {                              // S_u partial per block
            float v = (tid < 128) ? lds[1024 + tid] : 0.f;
            #pragma unroll
            for (int off = 32; off > 0; off >>= 1) v += __shfl_down(v, off, 64);
            if ((tid & 63) == 0) lds[1200 + (tid >> 6)] = v;
            __syncthreads();
            if (tid == 0) {
                float t2 = 0.f;
                #pragma unroll
                for (int q = 0; q < 16; ++q) t2 += lds[1200 + q];
                p.S_u_part[b] = t2;
            }
        }
    };

    // ---- M = W1@W2 (4 t-cols per block), c2 = b1@W2 (blocks RS..RS+63) -----
    auto precompute = [&]() {
        int q = b - RS;                               // 0..63
        {   int j = tid >> 2, t2 = tid & 3;           // W2 4-col slab -> LDS
            lds[tid] = p.W2[j * 256 + q * 4 + t2]; }
        __syncthreads();
        int wvi = tid >> 6, lane = tid & 63;
        for (int kr = 0; kr < 8; ++kr) {
            int k = wvi * 8 + kr;                     // 16 waves x 8 = 128 k
            float a0 = 0, a1 = 0, a2 = 0, a3 = 0;
            #pragma unroll
            for (int it = 0; it < 4; ++it) {
                int j = it * 64 + lane;
                float a = p.W1[k * 256 + j];          // coalesced row read
                a0 += a * lds[j*4+0]; a1 += a * lds[j*4+1];
                a2 += a * lds[j*4+2]; a3 += a * lds[j*4+3];
            }
            #pragma unroll
            for (int off = 32; off > 0; off >>= 1) {
                a0 += __shfl_down(a0, off, 64); a1 += __shfl_down(a1, off, 64);
                a2 += __shfl_down(a2, off, 64); a3 += __shfl_down(a3, off, 64);
            }
            if (lane == 0) {
                p.M[k * 256 + q*4 + 0] = a0; p.M[k * 256 + q*4 + 1] = a1;
                p.M[k * 256 + q*4 + 2] = a2; p.M[k * 256 + q*4 + 3] = a3;
            }
        }
        if (wvi == 0) {                               // c2 = b1 @ W2 slab
            float a0 = 0, a1 = 0, a2 = 0, a3 = 0;
            #pragma unroll
            for (int it = 0; it < 4; ++it) {
                int j = it * 64 + lane;
                float a = p.b1[j];
                a0 += a * lds[j*4+0]; a1 += a * lds[j*4+1];
                a2 += a * lds[j*4+2]; a3 += a * lds[j*4+3];
            }
            #pragma unroll
            for (int off = 32; off > 0; off >>= 1) {
                a0 += __shfl_down(a0, off, 64); a1 += __shfl_down(a1, off, 64);
                a2 += __shfl_down(a2, off, 64); a3 += __shfl_down(a3, off, 64);
            }
            if (lane == 0) {
                p.c2[q*4+0] = a0; p.c2[q*4+1] = a1;
                p.c2[q*4+2] = a2; p.c2[q*4+3] = a3;
            }
        }
    };

    // ---- warm head weights into caches (blocks 192..255) -------------------
    auto warm = [&]() {
        int q3 = b - 192;
        float sum = 0.f;
        if (tid < 512) sum += p.Wd1[q3 * 512 + tid];  // 64 x 512 = 32768
        if (b == 192) {
            if (tid < 256) sum += p.Wd2[tid];
            if (tid < 128) sum += p.bd1[tid];
            if (tid < 256) sum += p.b2[tid];
        }
        if (sum == 123456789.0f) p.S_u_part[255] = sum;  // never true: keep reads
    };

    // ---- feature pass: s_part[b][k] = sum wv[i]*x[i,k] ---------------------
    auto ksphase = [&]() {
        int k = tid & 127, h = tid >> 7;              // 8 rows x 128 cols
        float acc = 0.f;
        for (int i = b * 8 + h; i < N; i += 2048)
            acc += p.wv[i] * p.x[(size_t)i * D_IN + k];
        lds[h * 128 + k] = acc;
        __syncthreads();
        if (h == 0) {
            float t2 = 0.f;
            #pragma unroll
            for (int q = 0; q < 8; ++q) t2 += lds[q * 128 + k];
            p.s_part[b * 128 + k] = t2;
        }
    };

    // ---- head (block 0): fold s, S_u; g = (s@M + S_u*c2)/n + b2; z; softmax
    auto head = [&]() {
        int k = tid & 127, pg = tid >> 7;
        float acc = 0.f;
        #pragma unroll
        for (int q = 0; q < 32; ++q) acc += p.s_part[(pg * 32 + q) * 128 + k];
        lds[pg * 128 + k] = acc;
        float v = (tid < nfold) ? p.S_u_part[tid] : 0.f;
        #pragma unroll
        for (int off = 32; off > 0; off >>= 1) v += __shfl_down(v, off, 64);
        __syncthreads();
        if (pg == 0) {
            float t2 = 0.f;
            #pragma unroll
            for (int q = 0; q < 8; ++q) t2 += lds[q * 128 + k];
            lds[2048 + k] = t2;                       // s
        }
        if ((tid & 63) == 0) lds[2200 + (tid >> 6)] = v;
        __syncthreads();
        if (tid == 0) {
            float t2 = 0.f;
            #pragma unroll
            for (int q = 0; q < 16; ++q) t2 += lds[2200 + q];
            lds[2216] = t2;                           // S_u
        }
        __syncthreads();
        float S_u = lds[2216];
        if (tid < 256) {
            float a = 0.f;
            #pragma unroll 8
            for (int k2 = 0; k2 < 128; ++k2) a += lds[2048 + k2] * p.M[k2 * 256 + tid];
            lds[2304 + tid] = (a + S_u * p.c2[tid]) * p.inv_n + p.b2[tid];  // g
        }
        __syncthreads();
        if (tid < 128) {
            float a = 0.f;
            #pragma unroll 8
            for (int k2 = 0; k2 < 256; ++k2) a += lds[2304 + k2] * p.Wd1[k2 * 128 + tid];
            lds[2600 + tid] = fmaxf(a + p.bd1[tid], 0.f);                   // z
        }
        __syncthreads();
        float p0 = 0.f, p1 = 0.f;
        if (tid < 128) {
            float zt = lds[2600 + tid];
            p0 = zt * p.Wd2[tid * 2 + 0];
            p1 = zt * p.Wd2[tid * 2 + 1];
        }
        #pragma unroll
        for (int off = 32; off > 0; off >>= 1) {
            p0 += __shfl_down(p0, off, 64);
            p1 += __shfl_down(p1, off, 64);
        }
        if ((tid & 63) == 0) { lds[2700 + (tid >> 6)] = p0; lds[2720 + (tid >> 6)] = p1; }
        __syncthreads();
        if (tid == 0) {
            float l0 = 0.f, l1 = 0.f;
            #pragma unroll
            for (int q = 0; q < 16; ++q) { l0 += lds[2700 + q]; l1 += lds[2720 + q]; }
            l0 += p.bd2[0]; l1 += p.bd2[1];
            float m = fmaxf(l0, l1);
            float e0 = expf(l0 - m), e1 = expf(l1 - m);
            float inv = 1.0f / (e0 + e1);
            p.out[0] = e0 * inv;
            p.out[1] = e1 * inv;
        }
    };

    // ---------------- phase schedule (7 grid syncs) -------------------------
    if (b < RS) scatter(p.col, p.row, 0);             // deg by col
    else if (b < 192) precompute();                   // M, c2 (overlapped)
    else warm();                                      // Wd* cache warm
    grid.sync();
    fold(0);                                          // -> dinv
    grid.sync();
    if (b < RS) scatter(p.row, p.col, 1);             // gather dinv[c]
    grid.sync();
    fold(1);                                          // -> u, S_u partials
    grid.sync();
    if (b < RS) scatter(p.row, p.col, 2);             // gather dinv[c]*u[c]
    grid.sync();
    fold(2);                                          // -> wv
    grid.sync();
    ksphase();                                        // -> s_part
    grid.sync();
    if (b == 0) head();                               // -> out
}

extern "C" void kernel_launch(void* const* d_in, const int* in_sizes, int n_in,
                              void* d_out, int out_size, void* d_ws, size_t ws_size,
                              hipStream_t stream) {
    const int N = in_sizes[0] / D_IN;      // 20000
    const int E = in_sizes[1] / 2;         // 640000
    const int* ei = (const int*)d_in[1];

    Params prm;
    prm.x   = (const float*)d_in[0];
    prm.row = ei;
    prm.col = ei + E;
    prm.w   = (const float*)d_in[2];
    prm.W1  = (const float*)d_in[3];
    prm.b1  = (const float*)d_in[4];
    prm.W2  = (const float*)d_in[5];
    prm.b2  = (const float*)d_in[6];
    prm.Wd1 = (const float*)d_in[7];
    prm.bd1 = (const float*)d_in[8];
    prm.Wd2 = (const float*)d_in[9];
    prm.bd2 = (const float*)d_in[10];
    prm.out = (float*)d_out;

    // workspace (floats); everything is written before read — no memset
    float* ws    = (float*)d_ws;
    prm.part     = ws;                                 // RS*N
    prm.dinv     = prm.part + (size_t)RS * N;          // N
    prm.u        = prm.dinv + N;                       // N
    prm.wv       = prm.u + N;                          // N
    prm.s_part   = prm.wv + N;                         // 256*128
    prm.S_u_part = prm.s_part + 256 * D_IN;            // 256
    prm.M        = prm.S_u_part + 256;                 // 128*256
    prm.c2       = prm.M + D_IN * D_HID;               // 256
    prm.N = N; prm.E = E; prm.inv_n = 1.0f / (float)N;

    void* args[] = { &prm };
    hipLaunchCooperativeKernel((const void*)k_fused, dim3(256), dim3(1024),
                               args, 0, stream);
}

// Round 6
// 160.976 us; speedup vs baseline: 2.2524x; 2.2524x over previous
//
#include <hip/hip_runtime.h>
#include <hip/hip_bf16.h>

// GCN forward, algebraically collapsed (no nonlinearity between convs, mean pool):
//   g = (1/n)*((A^T u)^T X)@W1@W2 + (1/n)*(sum u)*(b1@W2) + b2,  A = D^-1/2(Adj+I)D^-1/2
// Round 6: revert cooperative fusion (grid.sync ~30us each on 8 XCDs).
// Split dispatches; scatter owns ONE bin-range per block (64 replicas/range,
// 4x less partial traffic); M=W1@W2 precompute rides on fold(0)'s spare
// blocks; k_s + folds + head fused in k_tail with a light device-scope
// counter barrier (most blocks exit after phase A).

#define D_IN 128
#define D_HID 256
#define D_DENSE 128
#define R0 10240          // range-0 size (floats; 40 KB LDS)
#define NSL 64            // edge slices == replicas per range
#define NFOLD 79          // ceil(20000/256) fold blocks

// ---- edge scatter: block = (slice, range); LDS histogram of own range -----
// mode 0: bin[col[e]] += w[e]
// mode 1: bin[row[e]] += w[e]*dinv[col[e]]
// mode 2: bin[row[e]] += w[e]*dinv[col[e]]*u[col[e]]
__global__ __launch_bounds__(1024) void k_scatter(
    const int* __restrict__ tgt, const int* __restrict__ src,
    const float* __restrict__ w, const float* __restrict__ dinv,
    const float* __restrict__ u, float* __restrict__ part,
    int E, int N, int mode) {
    __shared__ float acc[R0];
    const int range = blockIdx.x & 1;
    const int slice = blockIdx.x >> 1;           // 0..NSL-1
    const int base  = range ? R0 : 0;
    const int lim   = range ? (N - R0) : R0;
    if (lim <= 0) return;
    const int per = (E + NSL - 1) / NSL;
    const int e0 = slice * per, e1 = min(e0 + per, E);
    float* outp = part + (range ? (size_t)NSL * R0 + (size_t)slice * lim
                                : (size_t)slice * lim);
    for (int i = threadIdx.x; i < lim; i += 1024) acc[i] = 0.f;
    __syncthreads();
    for (int e = e0 + threadIdx.x; e < e1; e += 1024) {
        int t = tgt[e] - base;
        if ((unsigned)t < (unsigned)lim) {
            float v = w[e];
            if (mode != 0) {
                int c = src[e];
                float dc = dinv[c];
                v *= (mode == 2) ? dc * u[c] : dc;
            }
            atomicAdd(&acc[t], v);               // LDS atomic
        }
    }
    __syncthreads();
    for (int i = threadIdx.x; i < lim; i += 1024) outp[i] = acc[i];
}

// ---- fold 64 replicas + node math; blocks >= NFOLD do M=W1@W2 (mode 0) ----
__global__ __launch_bounds__(1024) void k_fold(
    const float* __restrict__ part, float* __restrict__ dinv,
    float* __restrict__ u, float* __restrict__ wv,
    float* __restrict__ S_u_part,
    const float* __restrict__ W1, const float* __restrict__ b1,
    const float* __restrict__ W2, float* __restrict__ M, float* __restrict__ c2,
    int N, int mode) {
    __shared__ float lds[1056];
    const int b = blockIdx.x, tid = threadIdx.x;

    if (b >= NFOLD) {                            // ---- M / c2 precompute ----
        int q = b - NFOLD;                       // 0..63: 4 cols of M each
        lds[tid] = W2[(tid >> 2) * 256 + q * 4 + (tid & 3)];
        __syncthreads();
        int wvi = tid >> 6, lane = tid & 63;
        for (int kr = 0; kr < 8; ++kr) {
            int k = wvi * 8 + kr;                // 16 waves x 8 = 128 rows
            float a0 = 0, a1 = 0, a2 = 0, a3 = 0;
            #pragma unroll
            for (int it = 0; it < 4; ++it) {
                int j = it * 64 + lane;
                float a = W1[k * 256 + j];
                a0 += a * lds[j*4+0]; a1 += a * lds[j*4+1];
                a2 += a * lds[j*4+2]; a3 += a * lds[j*4+3];
            }
            #pragma unroll
            for (int off = 32; off > 0; off >>= 1) {
                a0 += __shfl_down(a0, off, 64); a1 += __shfl_down(a1, off, 64);
                a2 += __shfl_down(a2, off, 64); a3 += __shfl_down(a3, off, 64);
            }
            if (lane == 0) {
                M[k * 256 + q*4 + 0] = a0; M[k * 256 + q*4 + 1] = a1;
                M[k * 256 + q*4 + 2] = a2; M[k * 256 + q*4 + 3] = a3;
            }
        }
        if (wvi == 0) {                          // c2 = b1 @ W2 slab
            float a0 = 0, a1 = 0, a2 = 0, a3 = 0;
            #pragma unroll
            for (int it = 0; it < 4; ++it) {
                int j = it * 64 + lane;
                float a = b1[j];
                a0 += a * lds[j*4+0]; a1 += a * lds[j*4+1];
                a2 += a * lds[j*4+2]; a3 += a * lds[j*4+3];
            }
            #pragma unroll
            for (int off = 32; off > 0; off >>= 1) {
                a0 += __shfl_down(a0, off, 64); a1 += __shfl_down(a1, off, 64);
                a2 += __shfl_down(a2, off, 64); a3 += __shfl_down(a3, off, 64);
            }
            if (lane == 0) {
                c2[q*4+0] = a0; c2[q*4+1] = a1;
                c2[q*4+2] = a2; c2[q*4+3] = a3;
            }
        }
        return;
    }

    // ---- replica fold: 256 nodes/block, 4 rgroups x 16 replicas -----------
    const int j = tid & 255, rg = tid >> 8;
    const int i = b * 256 + j;
    const bool act = i < N;
    const int R1 = N - R0;
    float sv = 0.f;
    if (act) {
        const float* pp;
        size_t st;
        if (i < R0) { pp = part + i;                          st = R0; }
        else        { pp = part + (size_t)NSL * R0 + (i - R0); st = R1; }
        pp += (size_t)rg * 16 * st;
        #pragma unroll
        for (int r = 0; r < 16; ++r) sv += pp[(size_t)r * st];
    }
    lds[rg * 256 + j] = sv;
    __syncthreads();
    float ui = 0.f;
    if (rg == 0) {
        float tot = lds[j] + lds[256 + j] + lds[512 + j] + lds[768 + j];
        if (act) {
            if (mode == 0)      dinv[i] = rsqrtf(tot + 1.0f);           // +1 self-loop
            else if (mode == 1) { float d = dinv[i]; ui = d * (tot + d); u[i] = ui; }
            else                { float d = dinv[i]; wv[i] = d * (tot + d * u[i]); }
        }
    }
    if (mode == 1) {                              // S_u partial per block
        float v = ui;                             // nonzero only in waves 0..3
        #pragma unroll
        for (int off = 32; off > 0; off >>= 1) v += __shfl_down(v, off, 64);
        if (tid < 256 && (tid & 63) == 0) lds[1024 + (tid >> 6)] = v;
        __syncthreads();
        if (tid == 0)
            S_u_part[b] = lds[1024] + lds[1025] + lds[1026] + lds[1027];
    }
}

// ---- barrier helpers (device-scope counter in d_ws) ------------------------
__device__ __forceinline__ void g_arrive(unsigned* ctr) {
    __syncthreads();
    if (threadIdx.x == 0)
        __hip_atomic_fetch_add(ctr, 1u, __ATOMIC_RELEASE, __HIP_MEMORY_SCOPE_AGENT);
}
__device__ __forceinline__ void g_wait(unsigned* ctr, unsigned target) {
    if (threadIdx.x == 0) {
        while (__hip_atomic_load(ctr, __ATOMIC_ACQUIRE, __HIP_MEMORY_SCOPE_AGENT) < target)
            __builtin_amdgcn_s_sleep(2);
    }
    __syncthreads();
}

// ---- tail: feature contraction + folds + head, one kernel ------------------
// 256 blocks x 256 threads, all co-resident (<=256 CUs). Counter targets:
// 256 (phase A), 272 (B: 16 head blocks), 288 (C).
__global__ __launch_bounds__(256) void k_tail(
    const float* __restrict__ x, const float* __restrict__ wv,
    const float* __restrict__ S_u_part, const float* __restrict__ M,
    const float* __restrict__ c2, const float* __restrict__ b2,
    const float* __restrict__ Wd1, const float* __restrict__ bd1,
    const float* __restrict__ Wd2, const float* __restrict__ bd2,
    float* __restrict__ s_part, float* __restrict__ g_part,
    float* __restrict__ z_part, float* __restrict__ S_u_g,
    unsigned* __restrict__ ctr, float* __restrict__ out,
    int N, float inv_n) {
    __shared__ float sh[256];
    __shared__ float ss[128];
    __shared__ float gv[16];
    const int b = blockIdx.x, tid = threadIdx.x;
    const int k = tid & 127, h = tid >> 7;

    // ---- phase A: s_part[b][k] = sum over rows (b*2+h + 512m) wv*x --------
    float acc = 0.f;
    for (int i = b * 2 + h; i < N; i += 512)
        acc += wv[i] * x[(size_t)i * D_IN + k];
    sh[h * 128 + k] = acc;
    __syncthreads();
    if (h == 0) s_part[b * 128 + k] = sh[k] + sh[128 + k];
    g_arrive(ctr);
    if (b >= 16) return;
    g_wait(ctr, 256);

    // ---- phase B: fold s; block b computes g_part rows [8b,8b+8) ----------
    {
        float a2 = 0.f;
        for (int q = 0; q < 128; ++q)
            a2 += s_part[(h * 128 + q) * 128 + k];
        sh[h * 128 + k] = a2;
        __syncthreads();
        if (h == 0) ss[k] = sh[k] + sh[128 + k];          // s[k]
        if (b == 0) {                                      // fold S_u (79 parts)
            float v = (tid < NFOLD) ? S_u_part[tid] : 0.f;
            #pragma unroll
            for (int off = 32; off > 0; off >>= 1) v += __shfl_down(v, off, 64);
            if ((tid & 63) == 0) sh[(tid >> 6)] = v;       // waves 0..3 -> sh[0..3]
        }
        __syncthreads();
        if (b == 0 && tid == 0)
            S_u_g[0] = sh[0] + sh[1] + sh[2] + sh[3];
        float gp = 0.f;
        #pragma unroll
        for (int kk = 0; kk < 8; ++kk)
            gp += ss[b * 8 + kk] * M[(b * 8 + kk) * 256 + tid];
        g_part[b * 256 + tid] = gp;
    }
    g_arrive(ctr);
    g_wait(ctr, 272);

    // ---- phase C: fold g slice [16b,16b+16); z_part[b][t<128] -------------
    {
        if (tid < 16) {
            int kk = b * 16 + tid;
            float gval = 0.f;
            #pragma unroll
            for (int p2 = 0; p2 < 16; ++p2) gval += g_part[p2 * 256 + kk];
            gv[tid] = (gval + S_u_g[0] * c2[kk]) * inv_n + b2[kk];
        }
        __syncthreads();
        if (tid < 128) {
            float z = 0.f;
            #pragma unroll
            for (int kk = 0; kk < 16; ++kk)
                z += gv[kk] * Wd1[(b * 16 + kk) * D_DENSE + tid];
            z_part[b * 128 + tid] = z;
        }
    }
    g_arrive(ctr);
    if (b != 0) return;
    g_wait(ctr, 288);

    // ---- phase D: fold z, relu, logits, softmax (block 0) -----------------
    float p0 = 0.f, p1 = 0.f;
    if (tid < 128) {
        float zr = bd1[tid];
        #pragma unroll
        for (int p2 = 0; p2 < 16; ++p2) zr += z_part[p2 * 128 + tid];
        float zt = fmaxf(zr, 0.f);
        p0 = zt * Wd2[tid * 2 + 0];
        p1 = zt * Wd2[tid * 2 + 1];
    }
    #pragma unroll
    for (int off = 32; off > 0; off >>= 1) {
        p0 += __shfl_down(p0, off, 64);
        p1 += __shfl_down(p1, off, 64);
    }
    if ((tid & 63) == 0) { sh[tid >> 6] = p0; sh[16 + (tid >> 6)] = p1; }
    __syncthreads();
    if (tid == 0) {
        float l0 = sh[0] + sh[1] + sh[2] + sh[3] + bd2[0];
        float l1 = sh[16] + sh[17] + sh[18] + sh[19] + bd2[1];
        float m = fmaxf(l0, l1);
        float e0 = expf(l0 - m), e1 = expf(l1 - m);
        float inv = 1.0f / (e0 + e1);
        out[0] = e0 * inv;
        out[1] = e1 * inv;
    }
}

extern "C" void kernel_launch(void* const* d_in, const int* in_sizes, int n_in,
                              void* d_out, int out_size, void* d_ws, size_t ws_size,
                              hipStream_t stream) {
    const float* x   = (const float*)d_in[0];
    const int*   ei  = (const int*)  d_in[1];
    const float* w   = (const float*)d_in[2];
    const float* W1  = (const float*)d_in[3];
    const float* b1  = (const float*)d_in[4];
    const float* W2  = (const float*)d_in[5];
    const float* b2  = (const float*)d_in[6];
    const float* Wd1 = (const float*)d_in[7];
    const float* bd1 = (const float*)d_in[8];
    const float* Wd2 = (const float*)d_in[9];
    const float* bd2 = (const float*)d_in[10];
    float* out = (float*)d_out;

    const int N = in_sizes[0] / D_IN;      // 20000
    const int E = in_sizes[1] / 2;         // 640000
    const int* row = ei;
    const int* col = ei + E;

    // workspace layout (floats). Everything except ctr is written before read.
    float* ws     = (float*)d_ws;
    unsigned* ctr = (unsigned*)ws;                         // 16 slots
    float* part   = ws + 16;                               // NSL*N (both ranges)
    float* dinv   = part + (size_t)NSL * N;                // N
    float* u      = dinv + N;                              // N
    float* wv     = u + N;                                 // N
    float* s_part = wv + N;                                // 256*128
    float* S_u_p  = s_part + 256 * D_IN;                   // NFOLD
    float* S_u_g  = S_u_p + 128;                           // 1
    float* M      = S_u_g + 1;                             // 128*256
    float* c2     = M + D_IN * D_HID;                      // 256
    float* g_part = c2 + D_HID;                            // 16*256
    float* z_part = g_part + 16 * D_HID;                   // 16*128

    hipMemsetAsync(ctr, 0, 64, stream);                    // barrier counter

    // pass 1: deg by col -> dinv; spare blocks compute M=W1@W2, c2=b1@W2
    k_scatter<<<2 * NSL, 1024, 0, stream>>>(col, row, w, dinv, u, part, E, N, 0);
    k_fold<<<NFOLD + 64, 1024, 0, stream>>>(part, dinv, u, wv, S_u_p,
                                            W1, b1, W2, M, c2, N, 0);
    // pass 2: by row, gather dinv[col] -> u, S_u partials
    k_scatter<<<2 * NSL, 1024, 0, stream>>>(row, col, w, dinv, u, part, E, N, 1);
    k_fold<<<NFOLD, 1024, 0, stream>>>(part, dinv, u, wv, S_u_p,
                                       W1, b1, W2, M, c2, N, 1);
    // pass 3: by row, gather dinv[col]*u[col] -> wv
    k_scatter<<<2 * NSL, 1024, 0, stream>>>(row, col, w, dinv, u, part, E, N, 2);
    k_fold<<<NFOLD, 1024, 0, stream>>>(part, dinv, u, wv, S_u_p,
                                       W1, b1, W2, M, c2, N, 2);
    // feature contraction + head (internal light barriers)
    k_tail<<<256, 256, 0, stream>>>(x, wv, S_u_p, M, c2, b2, Wd1, bd1, Wd2, bd2,
                                    s_part, g_part, z_part, S_u_g, ctr, out,
                                    N, 1.0f / (float)N);
}